// Round 8
// baseline (398.715 us; speedup 1.0000x reference)
//
#include <hip/hip_runtime.h>

#define N_NODES 50000
#define N_EDGES 800000
#define IN_CH 128
#define HID_CH 256
#define OUT_CH 128

constexpr int TOTAL_E = N_EDGES + N_NODES;       // incl self loops (compacted col)
constexpr int EPB_F = 400;                       // edges per fill chunk
constexpr int FILL_BLOCKS = N_EDGES / EPB_F;     // 2000 (exact), g = b & 7
constexpr int TOTG = 8 * N_NODES;                // g-major count array size
constexpr int SCAN_BLK = 1024;
constexpr int NBG = (TOTG + SCAN_BLK - 1) / SCAN_BLK;     // 391
constexpr int NBN = (N_NODES + SCAN_BLK - 1) / SCAN_BLK;  // 49

typedef __attribute__((ext_vector_type(8))) short bf16x8;
typedef __attribute__((ext_vector_type(4))) float f32x4;
typedef __attribute__((ext_vector_type(4))) unsigned int u32x4;

// ---------------- bf16 helpers ----------------

__device__ __forceinline__ unsigned int bf16rn(float x) {
    unsigned int u = __float_as_uint(x);
    return (u + 0x7fffu + ((u >> 16) & 1u)) >> 16;   // round-to-nearest-even
}

__device__ __forceinline__ void split2(float x0, float x1,
                                       unsigned int& h, unsigned int& l) {
    unsigned int h0 = bf16rn(x0), h1 = bf16rn(x1);
    float f0 = __uint_as_float(h0 << 16), f1 = __uint_as_float(h1 << 16);
    unsigned int l0 = bf16rn(x0 - f0), l1 = bf16rn(x1 - f1);
    h = h0 | (h1 << 16);
    l = l0 | (l1 << 16);
}

__device__ __forceinline__ bf16x8 asbf(u32x4 v) {
    return __builtin_bit_cast(bf16x8, v);
}

// ---------------- fp32 -> bf16 row copy (+ zero-init of cntG/curG) ----------------

__global__ void k_tobf_init(const float* __restrict__ x, unsigned short* __restrict__ xb,
                            int n8, int* __restrict__ cntG, int* __restrict__ curG) {
    int i = blockIdx.x * blockDim.x + threadIdx.x;
    if (i < TOTG) { cntG[i] = 0; curG[i] = 0; }
    if (i >= n8) return;
    const float4* p = (const float4*)(x + (size_t)i * 8);
    float4 a = p[0], b = p[1];
    u32x4 w;
    w.x = bf16rn(a.x) | (bf16rn(a.y) << 16);
    w.y = bf16rn(a.z) | (bf16rn(a.w) << 16);
    w.z = bf16rn(b.x) | (bf16rn(b.y) << 16);
    w.w = bf16rn(b.z) | (bf16rn(b.w) << 16);
    *(u32x4*)(xb + (size_t)i * 8) = w;
}

// ------------- CSR construction -------------
// Producer: 8 g-major planes (XCD-local scatter via b%8). Consumer: k_compact
// folds planes into a flat per-node CSR (col, wgt, offN, len) with the self
// loop appended (w = dis[v]^2).

__global__ void k_histG(const int* __restrict__ dst, int* __restrict__ cntG) {
    int e = blockIdx.x * blockDim.x + threadIdx.x;
    if (e < N_EDGES) {
        int g = (e / EPB_F) & 7;
        atomicAdd(&cntG[g * N_NODES + dst[e]], 1);
    }
}

// len[v] = 1 + in-degree (incl self loop); dis = rsqrt(len)
__global__ void k_deg(const int* __restrict__ cntG, int* __restrict__ len,
                      float* __restrict__ dis) {
    int v = blockIdx.x * blockDim.x + threadIdx.x;
    if (v < N_NODES) {
        int d = 1;
        #pragma unroll
        for (int g = 0; g < 8; ++g) d += cntG[g * N_NODES + v];
        len[v] = d;
        dis[v] = rsqrtf((float)d);
    }
}

__global__ void k_scan1(const int* __restrict__ cnt, int* __restrict__ incl,
                        int* __restrict__ part, int n) {
    __shared__ int s[SCAN_BLK];
    int t = threadIdx.x;
    int i = blockIdx.x * SCAN_BLK + t;
    int v = (i < n) ? cnt[i] : 0;
    s[t] = v; __syncthreads();
    for (int o = 1; o < SCAN_BLK; o <<= 1) {
        int a = (t >= o) ? s[t - o] : 0;
        __syncthreads();
        s[t] += a;
        __syncthreads();
    }
    if (i < n) incl[i] = s[t];
    if (t == SCAN_BLK - 1) part[blockIdx.x] = s[t];
}

// one launch scans both partial arrays: block 0 -> partG, block 1 -> partN
__global__ void k_scan22(int* __restrict__ partG, int* __restrict__ partN) {
    int* part = blockIdx.x ? partN : partG;
    int n     = blockIdx.x ? NBN : NBG;
    __shared__ int s[SCAN_BLK];
    int t = threadIdx.x;
    int v = (t < n) ? part[t] : 0;
    s[t] = v; __syncthreads();
    for (int o = 1; o < SCAN_BLK; o <<= 1) {
        int a = (t >= o) ? s[t - o] : 0;
        __syncthreads();
        s[t] += a;
        __syncthreads();
    }
    if (t < n) part[t] = s[t] - v;    // exclusive
}

// both exclusive scans finalized in place (+ sentinels)
__global__ void k_off2(int* __restrict__ inclG, const int* __restrict__ cntG,
                       const int* __restrict__ partG, int* __restrict__ inclN,
                       const int* __restrict__ lenN, const int* __restrict__ partN) {
    int i = blockIdx.x * blockDim.x + threadIdx.x;
    if (i < TOTG)       inclG[i] = partG[i >> 10] + inclG[i] - cntG[i];
    else if (i == TOTG) inclG[i] = N_EDGES;
    if (i < N_NODES)       inclN[i] = partN[i >> 10] + inclN[i] - lenN[i];
    else if (i == N_NODES) inclN[i] = TOTAL_E;
}

__global__ __launch_bounds__(128)
void k_fillG(const int* __restrict__ src, const int* __restrict__ dst,
             const int* __restrict__ offG, int* __restrict__ curG,
             int* __restrict__ colG) {
    int b = blockIdx.x;                 // chunk id == block id (2000 blocks)
    int g = b & 7;
    int e0 = b * EPB_F;
    for (int i = threadIdx.x; i < EPB_F; i += 128) {
        int e = e0 + i;
        int d = dst[e];
        int slot = g * N_NODES + d;
        int pos = offG[slot] + atomicAdd(&curG[slot], 1);
        colG[pos] = src[e];
    }
}

// fold 8 plane-segments of node v into contiguous col/wgt; append self loop
__global__ __launch_bounds__(256)
void k_compact(const int* __restrict__ offG, const int* __restrict__ colG,
               const int* __restrict__ offN, const float* __restrict__ dis,
               int* __restrict__ col, float* __restrict__ wgt) {
    int wid  = threadIdx.x >> 6;
    int lane = threadIdx.x & 63;
    int v = blockIdx.x * 4 + wid;       // grid exactly N_NODES/4
    float disv = dis[v];
    int pos = offN[v];
    #pragma unroll
    for (int g = 0; g < 8; ++g) {
        int s = offG[g * N_NODES + v];
        int e = offG[g * N_NODES + v + 1];   // g=7,v=last covered by sentinel
        for (int i = lane; i < e - s; i += 64) {
            int c = colG[s + i];
            col[pos + i] = c;
            wgt[pos + i] = dis[c] * disv;
        }
        pos += e - s;
    }
    if (lane == 0) { col[pos] = v; wgt[pos] = disv * disv; }
}

// ---- channel-sliced bf16 aggregation: out[v] = sum_e w_e * featb[c_e] ---------
// Slice s = blockIdx%8 covers channels [s*16, s*16+16) (32 B/row). Under the
// empirical blockIdx%8 -> XCD round-robin, each XCD gathers only a 1.6 MB table
// slice -> L2-resident. Block = 4 waves, 2 nodes/wave; per node: 8 edge slots x
// 4 lanes x 4 ch. Reduce over edge slots via shfl_xor(4/8/16).

template<bool BIAS, bool RELU>
__global__ __launch_bounds__(256)
void k_agg_sl(const unsigned short* __restrict__ featb, const int* __restrict__ col,
              const float* __restrict__ wgt, const int* __restrict__ offN,
              const int* __restrict__ len, const float* __restrict__ bias,
              float* __restrict__ out) {
    int s  = blockIdx.x & 7;
    int nb = blockIdx.x >> 3;
    int wid  = threadIdx.x >> 6;
    int lane = threadIdx.x & 63;
    int sub  = lane >> 5;               // node within wave
    int l    = lane & 31;
    int v = nb * 8 + wid * 2 + sub;     // grid = (N_NODES/8)*8 exact
    int start = offN[v];
    int lenv  = len[v];
    int ej = l >> 2;                    // edge slot 0..7
    int cq = l & 3;                     // channel quad within slice
    const unsigned short* fb = featb + s * 16 + cq * 4;
    float4 acc = make_float4(0.f, 0.f, 0.f, 0.f);
    for (int base = 0; base < lenv; base += 8) {
        int idx = base + ej;
        int c = 0; float w = 0.f;
        if (idx < lenv) { c = col[start + idx]; w = wgt[start + idx]; }
        uint2 d = *(const uint2*)(fb + (size_t)c * 128);
        acc.x = fmaf(w, __uint_as_float(d.x << 16),         acc.x);
        acc.y = fmaf(w, __uint_as_float(d.x & 0xffff0000u), acc.y);
        acc.z = fmaf(w, __uint_as_float(d.y << 16),         acc.z);
        acc.w = fmaf(w, __uint_as_float(d.y & 0xffff0000u), acc.w);
    }
    #pragma unroll
    for (int m = 4; m <= 16; m <<= 1) {
        acc.x += __shfl_xor(acc.x, m);
        acc.y += __shfl_xor(acc.y, m);
        acc.z += __shfl_xor(acc.z, m);
        acc.w += __shfl_xor(acc.w, m);
    }
    if (ej == 0) {
        float4 o = acc;
        if (BIAS) {
            float4 b = *(const float4*)&bias[s * 16 + cq * 4];
            o.x += b.x; o.y += b.y; o.z += b.z; o.w += b.w;
        }
        if (RELU) {
            o.x = fmaxf(o.x, 0.f); o.y = fmaxf(o.y, 0.f);
            o.z = fmaxf(o.z, 0.f); o.w = fmaxf(o.w, 0.f);
        }
        *(float4*)&out[(size_t)v * 128 + s * 16 + cq * 4] = o;
    }
}

// ---- W split into MFMA-fragment-ordered bf16 hi/lo --------------------------
// Fragment layout (16x16x32 bf16): B col n = lane&15, k = (lane>>4)*8 + i.

template<int K, int NC>
__global__ void k_wsplit(const float* __restrict__ W, u32x4* __restrict__ Wf) {
    constexpr int KT = K / 32, NT = NC / 16;
    int tid = blockIdx.x * blockDim.x + threadIdx.x;
    if (tid >= KT * NT * 64) return;
    int lane = tid & 63;
    int ntk  = tid >> 6;           // kt*NT + nt
    int kt = ntk / NT, nt = ntk % NT;
    int kb = kt * 32 + (lane >> 4) * 8;
    int n  = nt * 16 + (lane & 15);
    unsigned int hh[4], ll[4];
    #pragma unroll
    for (int j = 0; j < 4; ++j) {
        float x0 = W[(size_t)(kb + 2 * j) * NC + n];
        float x1 = W[(size_t)(kb + 2 * j + 1) * NC + n];
        split2(x0, x1, hh[j], ll[j]);
    }
    Wf[(size_t)(ntk * 2 + 0) * 64 + lane] = (u32x4){hh[0], hh[1], hh[2], hh[3]};
    Wf[(size_t)(ntk * 2 + 1) * 64 + lane] = (u32x4){ll[0], ll[1], ll[2], ll[3]};
}

// ---- MFMA GEMM: out[M,NC] = A[M,K] @ W[K,NC] (+bias, relu), split-bf16 3-pass ----

template<int K, int NC, bool BIAS, bool RELU, bool BF16OUT>
__global__ __launch_bounds__(128)
void k_gemm_mfma(const float* __restrict__ A, const u32x4* __restrict__ Wf,
                 const float* __restrict__ bias, void* __restrict__ outv, int M) {
    constexpr int KT = K / 32, NT = NC / 16, NTW = NT / 2;
    int lane = threadIdx.x & 63;
    int wid  = threadIdx.x >> 6;
    int lq = lane >> 4;            // 0..3
    int lr = lane & 15;
    int kq = lq * 8;
    int rbase = blockIdx.x * 32;
    int nt0 = wid * NTW;

    f32x4 acc[2][NTW];
    #pragma unroll
    for (int s = 0; s < 2; ++s)
        #pragma unroll
        for (int t = 0; t < NTW; ++t)
            acc[s][t] = (f32x4){0.f, 0.f, 0.f, 0.f};

    for (int kt = 0; kt < KT; ++kt) {
        bf16x8 ah[2], al[2];
        #pragma unroll
        for (int s = 0; s < 2; ++s) {
            int row = rbase + s * 16 + lr;
            const float* Ar = A + (size_t)min(row, M - 1) * K + kt * 32 + kq;
            float4 u = *(const float4*)Ar;
            float4 v = *(const float4*)(Ar + 4);
            unsigned int h0, l0, h1, l1, h2, l2, h3, l3;
            split2(u.x, u.y, h0, l0); split2(u.z, u.w, h1, l1);
            split2(v.x, v.y, h2, l2); split2(v.z, v.w, h3, l3);
            ah[s] = asbf((u32x4){h0, h1, h2, h3});
            al[s] = asbf((u32x4){l0, l1, l2, l3});
        }
        #pragma unroll
        for (int t = 0; t < NTW; ++t) {
            int nt = nt0 + t;
            const u32x4* wp = Wf + (size_t)((kt * NT + nt) * 2) * 64 + lane;
            bf16x8 bh = asbf(wp[0]);
            bf16x8 bl = asbf(wp[64]);
            // D = Ah*Wh + Al*Wh + Ah*Wl  (drop Al*Wl ~ 2^-18)
            acc[0][t] = __builtin_amdgcn_mfma_f32_16x16x32_bf16(ah[0], bh, acc[0][t], 0, 0, 0);
            acc[1][t] = __builtin_amdgcn_mfma_f32_16x16x32_bf16(ah[1], bh, acc[1][t], 0, 0, 0);
            acc[0][t] = __builtin_amdgcn_mfma_f32_16x16x32_bf16(al[0], bh, acc[0][t], 0, 0, 0);
            acc[1][t] = __builtin_amdgcn_mfma_f32_16x16x32_bf16(al[1], bh, acc[1][t], 0, 0, 0);
            acc[0][t] = __builtin_amdgcn_mfma_f32_16x16x32_bf16(ah[0], bl, acc[0][t], 0, 0, 0);
            acc[1][t] = __builtin_amdgcn_mfma_f32_16x16x32_bf16(ah[1], bl, acc[1][t], 0, 0, 0);
        }
    }

    // epilogue: D col = lane&15, row = (lane>>4)*4 + j
    #pragma unroll
    for (int t = 0; t < NTW; ++t) {
        int colg = (nt0 + t) * 16 + lr;
        float bv = BIAS ? bias[colg] : 0.f;
        #pragma unroll
        for (int s = 0; s < 2; ++s) {
            #pragma unroll
            for (int j = 0; j < 4; ++j) {
                int row = rbase + s * 16 + lq * 4 + j;
                if (row < M) {
                    float o = acc[s][t][j] + bv;
                    if (RELU) o = fmaxf(o, 0.f);
                    if (BF16OUT)
                        ((unsigned short*)outv)[(size_t)row * NC + colg] = (unsigned short)bf16rn(o);
                    else
                        ((float*)outv)[(size_t)row * NC + colg] = o;
                }
            }
        }
    }
}

// ---------------- launch ----------------

extern "C" void kernel_launch(void* const* d_in, const int* in_sizes, int n_in,
                              void* d_out, int out_size, void* d_ws, size_t ws_size,
                              hipStream_t stream) {
    const float* x   = (const float*)d_in[0];
    const int*   ei  = (const int*)d_in[1];
    const int*   src = ei;
    const int*   dst = ei + N_EDGES;
    const float* W1  = (const float*)d_in[3];
    const float* b1  = (const float*)d_in[4];
    const float* W2  = (const float*)d_in[5];
    const float* b2  = (const float*)d_in[6];
    float* out = (float*)d_out;

    char* ws = (char*)d_ws;
    size_t o = 0;
    auto carve = [&](size_t bytes) {
        void* p = ws + o;
        o += (bytes + 255) & ~(size_t)255;
        return p;
    };
    int*   cntG   = (int*)  carve((size_t)TOTG * 4);
    int*   curG   = (int*)  carve((size_t)TOTG * 4);
    int*   inclG  = (int*)  carve((size_t)(TOTG + 1) * 4);  // becomes offG in place
    int*   partG  = (int*)  carve(SCAN_BLK * 4);
    int*   len    = (int*)  carve(N_NODES * 4);
    int*   inclN  = (int*)  carve((size_t)(N_NODES + 1) * 4); // becomes offN in place
    int*   partN  = (int*)  carve(SCAN_BLK * 4);
    float* dis    = (float*)carve(N_NODES * 4);
    int*   col    = (int*)  carve((size_t)TOTAL_E * 4);      // compacted CSR (+self)
    float* wgt    = (float*)carve((size_t)TOTAL_E * 4);      // per-edge weights
    float* agg1   = (float*)carve((size_t)N_NODES * 128 * 4);
    float* h1     = (float*)carve((size_t)N_NODES * 256 * 4);
    u32x4* Wf1    = (u32x4*)carve((size_t)(IN_CH/32) * (HID_CH/16) * 2 * 64 * 16);
    u32x4* Wf2    = (u32x4*)carve((size_t)(HID_CH/32) * (OUT_CH/16) * 2 * 64 * 16);
    int*   offG   = inclG;                 // in-place exclusive scan
    int*   offN   = inclN;
    // Aliases (lifetimes by launch order):
    //   xb   aliases h1  : written by k_tobf_init, dead after agg1; h1 by gemm1
    //   colG aliases agg1: written by fillG, dead after compact; agg1 by agg1-pass
    //   t2b  aliases agg1: agg1 dead after gemm1; t2b by gemm2, read by agg2
    unsigned short* xb  = (unsigned short*)h1;
    int*            colG = (int*)agg1;
    unsigned short* t2b = (unsigned short*)agg1;

    const int B = 256;
    k_tobf_init <<<(N_NODES * 128 / 8 + B - 1) / B, B, 0, stream>>>(
        x, xb, N_NODES * 128 / 8, cntG, curG);
    k_histG <<<(N_EDGES + B - 1) / B, B, 0, stream>>>(dst, cntG);
    k_deg   <<<(N_NODES + B - 1) / B, B, 0, stream>>>(cntG, len, dis);
    k_scan1 <<<NBG, SCAN_BLK, 0, stream>>>(cntG, inclG, partG, TOTG);
    k_scan1 <<<NBN, SCAN_BLK, 0, stream>>>(len, inclN, partN, N_NODES);
    k_scan22<<<2, SCAN_BLK, 0, stream>>>(partG, partN);
    k_off2  <<<(TOTG + 1 + B - 1) / B, B, 0, stream>>>(inclG, cntG, partG,
                                                       inclN, len, partN);
    k_fillG   <<<FILL_BLOCKS, 128, 0, stream>>>(src, dst, offG, curG, colG);
    k_compact <<<N_NODES / 4, 256, 0, stream>>>(offG, colG, offN, dis, col, wgt);

    k_wsplit<IN_CH,  HID_CH><<<( (IN_CH/32)*(HID_CH/16)*64 + B - 1) / B, B, 0, stream>>>(W1, Wf1);
    k_wsplit<HID_CH, OUT_CH><<<( (HID_CH/32)*(OUT_CH/16)*64 + B - 1) / B, B, 0, stream>>>(W2, Wf2);

    // layer 1: agg1 = A xb ; h1 = relu(agg1 @ W1 + b1)   (clobbers xb, now dead)
    k_agg_sl<false, false><<<(N_NODES / 8) * 8, 256, 0, stream>>>(
        xb, col, wgt, offN, len, nullptr, agg1);
    k_gemm_mfma<IN_CH, HID_CH, true, true, false>
        <<<(N_NODES + 31) / 32, 128, 0, stream>>>(agg1, Wf1, b1, h1, N_NODES);

    // layer 2: t2b = bf16(h1 @ W2) ; out = relu(A t2b + b2)
    k_gemm_mfma<HID_CH, OUT_CH, false, false, true>
        <<<(N_NODES + 31) / 32, 128, 0, stream>>>(h1, Wf2, nullptr, t2b, N_NODES);
    k_agg_sl<true, true><<<(N_NODES / 8) * 8, 256, 0, stream>>>(
        t2b, col, wgt, offN, len, b2, out);
}

// Round 9
// 165.718 us; speedup vs baseline: 2.4060x; 2.4060x over previous
//
#include <hip/hip_runtime.h>

#define N_NODES 50000
#define N_EDGES 800000
#define IN_CH 128
#define HID_CH 256
#define OUT_CH 128

constexpr int TOTAL_E = N_EDGES + N_NODES;       // edges + self loops in CSR
constexpr int NBKT = 196;                        // buckets of 256 nodes (dst>>8)
constexpr int NBLK_BIN = 128;                    // binning blocks
constexpr int EPB_BIN = N_EDGES / NBLK_BIN;      // 6250 (exact)
constexpr int CNT2D = NBKT * NBLK_BIN;           // 25088
constexpr int SCAN_BLK = 1024;
constexpr int NB_SC = (CNT2D + SCAN_BLK - 1) / SCAN_BLK;  // 25
constexpr int COLCAP = 5376;                     // bucket edges cap + 256 selfloops

typedef __attribute__((ext_vector_type(8))) short bf16x8;
typedef __attribute__((ext_vector_type(4))) float f32x4;
typedef __attribute__((ext_vector_type(4))) unsigned int u32x4;

// ---------------- bf16 helpers ----------------

__device__ __forceinline__ unsigned int bf16rn(float x) {
    unsigned int u = __float_as_uint(x);
    return (u + 0x7fffu + ((u >> 16) & 1u)) >> 16;   // round-to-nearest-even
}

__device__ __forceinline__ void split2(float x0, float x1,
                                       unsigned int& h, unsigned int& l) {
    unsigned int h0 = bf16rn(x0), h1 = bf16rn(x1);
    float f0 = __uint_as_float(h0 << 16), f1 = __uint_as_float(h1 << 16);
    unsigned int l0 = bf16rn(x0 - f0), l1 = bf16rn(x1 - f1);
    h = h0 | (h1 << 16);
    l = l0 | (l1 << 16);
}

__device__ __forceinline__ bf16x8 asbf(u32x4 v) {
    return __builtin_bit_cast(bf16x8, v);
}

// ---------------- fp32 -> bf16 row copy ----------------

__global__ void k_tobf(const float* __restrict__ x, unsigned short* __restrict__ xb,
                       int n8) {
    int i = blockIdx.x * blockDim.x + threadIdx.x;
    if (i >= n8) return;
    const float4* p = (const float4*)(x + (size_t)i * 8);
    float4 a = p[0], b = p[1];
    u32x4 w;
    w.x = bf16rn(a.x) | (bf16rn(a.y) << 16);
    w.y = bf16rn(a.z) | (bf16rn(a.w) << 16);
    w.z = bf16rn(b.x) | (bf16rn(b.y) << 16);
    w.w = bf16rn(b.z) | (bf16rn(b.w) << 16);
    *(u32x4*)(xb + (size_t)i * 8) = w;
}

// ------------- CSR build: LDS radix binning (no global atomics, no scatter amp) -------------
// bucket = dst >> 8 (256 nodes each). k_count -> cnt2D[bkt][blk]; scan; k_bin
// scatters (src,dst) into exclusive per-(blk,bkt) chunks (bucket-major);
// k_csr builds each bucket's CSR segment entirely in LDS (hist, scan, scatter,
// self-loops) and streams out col/off/dis coalesced.

__global__ __launch_bounds__(256)
void k_count(const int* __restrict__ dst, int* __restrict__ cnt2D) {
    __shared__ int h[NBKT];
    int b = blockIdx.x, t = threadIdx.x;
    if (t < NBKT) h[t] = 0;
    __syncthreads();
    int e0 = b * EPB_BIN;
    for (int i = t; i < EPB_BIN; i += 256)
        atomicAdd(&h[dst[e0 + i] >> 8], 1);
    __syncthreads();
    if (t < NBKT) cnt2D[t * NBLK_BIN + b] = h[t];
}

__global__ void k_scan1(const int* __restrict__ cnt, int* __restrict__ incl,
                        int* __restrict__ part, int n) {
    __shared__ int s[SCAN_BLK];
    int t = threadIdx.x;
    int i = blockIdx.x * SCAN_BLK + t;
    int v = (i < n) ? cnt[i] : 0;
    s[t] = v; __syncthreads();
    for (int o = 1; o < SCAN_BLK; o <<= 1) {
        int a = (t >= o) ? s[t - o] : 0;
        __syncthreads();
        s[t] += a;
        __syncthreads();
    }
    if (i < n) incl[i] = s[t];
    if (t == SCAN_BLK - 1) part[blockIdx.x] = s[t];
}

__global__ void k_scan2(int* __restrict__ part, int n) {
    __shared__ int s[SCAN_BLK];
    int t = threadIdx.x;
    int v = (t < n) ? part[t] : 0;
    s[t] = v; __syncthreads();
    for (int o = 1; o < SCAN_BLK; o <<= 1) {
        int a = (t >= o) ? s[t - o] : 0;
        __syncthreads();
        s[t] += a;
        __syncthreads();
    }
    if (t < n) part[t] = s[t] - v;    // exclusive
}

__global__ void k_off(int* __restrict__ incl, const int* __restrict__ cnt,
                      const int* __restrict__ part, int n, int total) {
    int i = blockIdx.x * blockDim.x + threadIdx.x;
    if (i < n)       incl[i] = part[i >> 10] + incl[i] - cnt[i];
    else if (i == n) incl[i] = total;
}

__global__ __launch_bounds__(256)
void k_bin(const int* __restrict__ src, const int* __restrict__ dst,
           const int* __restrict__ off2D, int2* __restrict__ binned) {
    __shared__ int cur[NBKT];
    int b = blockIdx.x, t = threadIdx.x;
    if (t < NBKT) cur[t] = off2D[t * NBLK_BIN + b];
    __syncthreads();
    int e0 = b * EPB_BIN;
    for (int i = t; i < EPB_BIN; i += 256) {
        int d = dst[e0 + i];
        int pos = atomicAdd(&cur[d >> 8], 1);
        int2 p; p.x = src[e0 + i]; p.y = d;
        binned[pos] = p;
    }
}

__global__ __launch_bounds__(256)
void k_csr(const int2* __restrict__ binned, const int* __restrict__ off2D,
           int* __restrict__ col, int* __restrict__ off, float* __restrict__ dis) {
    __shared__ int cnt[256], sc[256], cur[256];
    __shared__ int colL[COLCAP];
    int kb = blockIdx.x, t = threadIdx.x;
    int base2 = off2D[kb * NBLK_BIN];
    int end2  = off2D[(kb + 1) * NBLK_BIN];   // kb==NBKT-1 hits sentinel
    int nE = end2 - base2;
    int nn = min(256, N_NODES - kb * 256);
    cnt[t] = 0;
    __syncthreads();
    for (int i = t; i < nE; i += 256)
        atomicAdd(&cnt[binned[base2 + i].y & 255], 1);
    __syncthreads();
    sc[t] = cnt[t];
    __syncthreads();
    for (int o = 1; o < 256; o <<= 1) {
        int a = (t >= o) ? sc[t - o] : 0;
        __syncthreads();
        sc[t] += a;
        __syncthreads();
    }
    int excl = sc[t] - cnt[t];
    cur[t] = excl + t;            // +t: one self-loop slot per preceding node
    __syncthreads();
    for (int i = t; i < nE; i += 256) {
        int2 p = binned[base2 + i];
        colL[atomicAdd(&cur[p.y & 255], 1)] = p.x;
    }
    __syncthreads();
    int v = kb * 256 + t;
    if (t < nn) {
        colL[cur[t]] = v;         // self loop at segment end
        off[v] = base2 + kb * 256 + excl + t;
        dis[v] = rsqrtf((float)(cnt[t] + 1));
    }
    if (kb == NBKT - 1 && t == 0) off[N_NODES] = TOTAL_E;
    __syncthreads();
    int tot = nE + nn, gbase = base2 + kb * 256;
    for (int i = t; i < tot; i += 256)
        col[gbase + i] = colL[i];
}

// ---- bf16 aggregation: out[v] = sum_{c} dis[c]*dis[v] * featb[c]  (F = 128) ----
// 4 waves/block, one node per wave. Lanes 0-31 edge j, lanes 32-63 edge j+1;
// each lane covers 4 channels (8 B load). Cross-half reduce via shfl_xor(32).

template<bool BIAS, bool RELU>
__global__ __launch_bounds__(256)
void k_agg_bf(const unsigned short* __restrict__ featb, const int* __restrict__ col,
              const int* __restrict__ off, const float* __restrict__ dis,
              const float* __restrict__ bias, float* __restrict__ out) {
    int wid  = threadIdx.x >> 6;
    int lane = threadIdx.x & 63;
    int v = blockIdx.x * 4 + wid;          // grid is exactly N_NODES/4
    int start = off[v];
    int lenv  = off[v + 1] - start;
    float disv = dis[v];
    int half = lane >> 5;
    int q    = lane & 31;
    float4 acc = make_float4(0.f, 0.f, 0.f, 0.f);
    for (int base = 0; base < lenv; base += 64) {
        int n = min(64, lenv - base);
        int   cv = 0;
        float wv = 0.f;
        if (lane < n) {
            cv = col[start + base + lane];
            wv = dis[cv] * disv;
        }
        auto pair = [&](int j) {
            int   c = __shfl(cv, j + half);   // j+half==n on odd tail -> w=0, c=0
            float w = __shfl(wv, j + half);
            uint2 d = *(const uint2*)&featb[(size_t)c * 128 + q * 4];
            acc.x = fmaf(w, __uint_as_float(d.x << 16),         acc.x);
            acc.y = fmaf(w, __uint_as_float(d.x & 0xffff0000u), acc.y);
            acc.z = fmaf(w, __uint_as_float(d.y << 16),         acc.z);
            acc.w = fmaf(w, __uint_as_float(d.y & 0xffff0000u), acc.w);
        };
        int j = 0;
        for (; j + 8 <= n; j += 8) { pair(j); pair(j + 2); pair(j + 4); pair(j + 6); }
        for (; j < n; j += 2) pair(j);
    }
    acc.x += __shfl_xor(acc.x, 32);
    acc.y += __shfl_xor(acc.y, 32);
    acc.z += __shfl_xor(acc.z, 32);
    acc.w += __shfl_xor(acc.w, 32);
    if (half == 0) {
        float4 o = acc;
        if (BIAS) {
            float4 b = *(const float4*)&bias[q * 4];
            o.x += b.x; o.y += b.y; o.z += b.z; o.w += b.w;
        }
        if (RELU) {
            o.x = fmaxf(o.x, 0.f); o.y = fmaxf(o.y, 0.f);
            o.z = fmaxf(o.z, 0.f); o.w = fmaxf(o.w, 0.f);
        }
        *(float4*)&out[(size_t)v * 128 + q * 4] = o;
    }
}

// ---- W split into MFMA-fragment-ordered bf16 hi/lo (both layers, one launch) ----
// Fragment layout (16x16x32 bf16): B col n = lane&15, k = (lane>>4)*8 + i.

template<int K, int NC>
__device__ __forceinline__ void wsplit_body(const float* __restrict__ W,
                                            u32x4* __restrict__ Wf, int tid) {
    constexpr int NT = NC / 16;
    int lane = tid & 63;
    int ntk  = tid >> 6;
    int kt = ntk / NT, nt = ntk % NT;
    int kb = kt * 32 + (lane >> 4) * 8;
    int n  = nt * 16 + (lane & 15);
    unsigned int hh[4], ll[4];
    #pragma unroll
    for (int j = 0; j < 4; ++j) {
        float x0 = W[(size_t)(kb + 2 * j) * NC + n];
        float x1 = W[(size_t)(kb + 2 * j + 1) * NC + n];
        split2(x0, x1, hh[j], ll[j]);
    }
    Wf[(size_t)(ntk * 2 + 0) * 64 + lane] = (u32x4){hh[0], hh[1], hh[2], hh[3]};
    Wf[(size_t)(ntk * 2 + 1) * 64 + lane] = (u32x4){ll[0], ll[1], ll[2], ll[3]};
}

__global__ void k_wsplit_both(const float* __restrict__ W1, u32x4* __restrict__ Wf1,
                              const float* __restrict__ W2, u32x4* __restrict__ Wf2) {
    int tid = blockIdx.x * blockDim.x + threadIdx.x;
    if (tid < 4096)      wsplit_body<IN_CH,  HID_CH>(W1, Wf1, tid);
    else if (tid < 8192) wsplit_body<HID_CH, OUT_CH>(W2, Wf2, tid - 4096);
}

// ---- Fused GEMM: t2 = relu(A@W1+b1) @ W2, A fp32 [M,128], t2 bf16 [M,128] ----
// 2 waves/block, 32 rows/block. h1 tile (32x256) lives only in LDS as bf16
// hi/lo planes (exact fp32 reconstruction), XOR-swizzled for bank-uniform
// ds_read_b128 in the second GEMM.

__global__ __launch_bounds__(128)
void k_gemm_fused(const float* __restrict__ A, const u32x4* __restrict__ Wf1,
                  const float* __restrict__ b1, const u32x4* __restrict__ Wf2,
                  unsigned short* __restrict__ outb, int M) {
    __shared__ unsigned short hh[32 * 256];
    __shared__ unsigned short hl[32 * 256];
    int lane = threadIdx.x & 63, wid = threadIdx.x >> 6;
    int lq = lane >> 4, lr = lane & 15, kq = lq * 8;
    int rbase = blockIdx.x * 32;

    // ---- GEMM1: 32x128 @ 128x256, split-bf16 3-pass ----
    f32x4 acc[2][8];
    #pragma unroll
    for (int s = 0; s < 2; ++s)
        #pragma unroll
        for (int t = 0; t < 8; ++t) acc[s][t] = (f32x4){0.f, 0.f, 0.f, 0.f};

    for (int kt = 0; kt < 4; ++kt) {
        bf16x8 ah[2], al[2];
        #pragma unroll
        for (int s = 0; s < 2; ++s) {
            int row = rbase + s * 16 + lr;
            const float* Ar = A + (size_t)min(row, M - 1) * IN_CH + kt * 32 + kq;
            float4 u = *(const float4*)Ar;
            float4 v = *(const float4*)(Ar + 4);
            unsigned int h0, l0, h1, l1, h2, l2, h3, l3;
            split2(u.x, u.y, h0, l0); split2(u.z, u.w, h1, l1);
            split2(v.x, v.y, h2, l2); split2(v.z, v.w, h3, l3);
            ah[s] = asbf((u32x4){h0, h1, h2, h3});
            al[s] = asbf((u32x4){l0, l1, l2, l3});
        }
        #pragma unroll
        for (int t = 0; t < 8; ++t) {
            int nt = wid * 8 + t;
            const u32x4* wp = Wf1 + (size_t)((kt * 16 + nt) * 2) * 64 + lane;
            bf16x8 bh = asbf(wp[0]);
            bf16x8 bl = asbf(wp[64]);
            acc[0][t] = __builtin_amdgcn_mfma_f32_16x16x32_bf16(ah[0], bh, acc[0][t], 0, 0, 0);
            acc[1][t] = __builtin_amdgcn_mfma_f32_16x16x32_bf16(ah[1], bh, acc[1][t], 0, 0, 0);
            acc[0][t] = __builtin_amdgcn_mfma_f32_16x16x32_bf16(al[0], bh, acc[0][t], 0, 0, 0);
            acc[1][t] = __builtin_amdgcn_mfma_f32_16x16x32_bf16(al[1], bh, acc[1][t], 0, 0, 0);
            acc[0][t] = __builtin_amdgcn_mfma_f32_16x16x32_bf16(ah[0], bl, acc[0][t], 0, 0, 0);
            acc[1][t] = __builtin_amdgcn_mfma_f32_16x16x32_bf16(ah[1], bl, acc[1][t], 0, 0, 0);
        }
    }

    // epilogue1: bias+relu, split to bf16 hi/lo in LDS (XOR-swizzled)
    #pragma unroll
    for (int t = 0; t < 8; ++t) {
        int colg = (wid * 8 + t) * 16 + lr;
        float bv = b1[colg];
        #pragma unroll
        for (int s = 0; s < 2; ++s) {
            #pragma unroll
            for (int j = 0; j < 4; ++j) {
                int row = s * 16 + lq * 4 + j;
                float o = fmaxf(acc[s][t][j] + bv, 0.f);
                unsigned int hi = bf16rn(o);
                float rem = o - __uint_as_float(hi << 16);
                unsigned int lo = bf16rn(rem);
                int e = (row * 256 + colg) ^ ((row & 7) << 3);
                hh[e] = (unsigned short)hi;
                hl[e] = (unsigned short)lo;
            }
        }
    }
    __syncthreads();

    // ---- GEMM2: 32x256 @ 256x128, A = exact h1 (hi+lo) from LDS ----
    f32x4 acc2[2][4];
    #pragma unroll
    for (int s = 0; s < 2; ++s)
        #pragma unroll
        for (int t = 0; t < 4; ++t) acc2[s][t] = (f32x4){0.f, 0.f, 0.f, 0.f};

    for (int kt = 0; kt < 8; ++kt) {
        bf16x8 ah[2], al[2];
        #pragma unroll
        for (int s = 0; s < 2; ++s) {
            int row = s * 16 + lr;
            int e = (row * 256 + kt * 32 + kq) ^ ((row & 7) << 3);
            ah[s] = *(const bf16x8*)&hh[e];
            al[s] = *(const bf16x8*)&hl[e];
        }
        #pragma unroll
        for (int t = 0; t < 4; ++t) {
            int nt = wid * 4 + t;
            const u32x4* wp = Wf2 + (size_t)((kt * 8 + nt) * 2) * 64 + lane;
            bf16x8 bh = asbf(wp[0]);
            bf16x8 bl = asbf(wp[64]);
            acc2[0][t] = __builtin_amdgcn_mfma_f32_16x16x32_bf16(ah[0], bh, acc2[0][t], 0, 0, 0);
            acc2[1][t] = __builtin_amdgcn_mfma_f32_16x16x32_bf16(ah[1], bh, acc2[1][t], 0, 0, 0);
            acc2[0][t] = __builtin_amdgcn_mfma_f32_16x16x32_bf16(al[0], bh, acc2[0][t], 0, 0, 0);
            acc2[1][t] = __builtin_amdgcn_mfma_f32_16x16x32_bf16(al[1], bh, acc2[1][t], 0, 0, 0);
            acc2[0][t] = __builtin_amdgcn_mfma_f32_16x16x32_bf16(ah[0], bl, acc2[0][t], 0, 0, 0);
            acc2[1][t] = __builtin_amdgcn_mfma_f32_16x16x32_bf16(ah[1], bl, acc2[1][t], 0, 0, 0);
        }
    }

    // epilogue2: t2 as bf16 (no bias/relu here; agg2 applies them)
    #pragma unroll
    for (int t = 0; t < 4; ++t) {
        int colg = (wid * 4 + t) * 16 + lr;
        #pragma unroll
        for (int s = 0; s < 2; ++s) {
            #pragma unroll
            for (int j = 0; j < 4; ++j) {
                int row = rbase + s * 16 + lq * 4 + j;
                if (row < M)
                    outb[(size_t)row * OUT_CH + colg] =
                        (unsigned short)bf16rn(acc2[s][t][j]);
            }
        }
    }
}

// ---------------- launch ----------------

extern "C" void kernel_launch(void* const* d_in, const int* in_sizes, int n_in,
                              void* d_out, int out_size, void* d_ws, size_t ws_size,
                              hipStream_t stream) {
    const float* x   = (const float*)d_in[0];
    const int*   ei  = (const int*)d_in[1];
    const int*   src = ei;
    const int*   dst = ei + N_EDGES;
    const float* W1  = (const float*)d_in[3];
    const float* b1  = (const float*)d_in[4];
    const float* W2  = (const float*)d_in[5];
    const float* b2  = (const float*)d_in[6];
    float* out = (float*)d_out;

    char* ws = (char*)d_ws;
    size_t o = 0;
    auto carve = [&](size_t bytes) {
        void* p = ws + o;
        o += (bytes + 255) & ~(size_t)255;
        return p;
    };
    int*   cnt2D  = (int*)  carve((size_t)CNT2D * 4);
    int*   incl2D = (int*)  carve((size_t)(CNT2D + 1) * 4);  // becomes off2D
    int*   part   = (int*)  carve(SCAN_BLK * 4);
    int*   off    = (int*)  carve((size_t)(N_NODES + 1) * 4);
    float* dis    = (float*)carve(N_NODES * 4);
    int*   col    = (int*)  carve((size_t)TOTAL_E * 4);
    float* agg1   = (float*)carve((size_t)N_NODES * 128 * 4);  // head hosts binned
    unsigned short* bfbuf = (unsigned short*)carve((size_t)N_NODES * 128 * 2);
    u32x4* Wf1    = (u32x4*)carve((size_t)4 * 16 * 2 * 64 * 16);
    u32x4* Wf2    = (u32x4*)carve((size_t)8 * 8 * 2 * 64 * 16);
    int*   off2D  = incl2D;                // in-place exclusive scan
    // Aliases (lifetimes by launch order):
    //   binned aliases agg1 : written by k_bin, read by k_csr, dead before agg1
    //   xb = bfbuf          : written by k_tobf, dead after agg-layer1
    //   t2b = bfbuf         : written by fused gemm (after xb dead), read by agg2
    int2*           binned = (int2*)agg1;
    unsigned short* xb     = bfbuf;
    unsigned short* t2b    = bfbuf;

    const int B = 256;
    k_tobf  <<<(N_NODES * 128 / 8 + B - 1) / B, B, 0, stream>>>(x, xb, N_NODES * 128 / 8);
    k_count <<<NBLK_BIN, 256, 0, stream>>>(dst, cnt2D);
    k_scan1 <<<NB_SC, SCAN_BLK, 0, stream>>>(cnt2D, incl2D, part, CNT2D);
    k_scan2 <<<1, SCAN_BLK, 0, stream>>>(part, NB_SC);
    k_off   <<<(CNT2D + 1 + B - 1) / B, B, 0, stream>>>(incl2D, cnt2D, part, CNT2D, N_EDGES);
    k_bin   <<<NBLK_BIN, 256, 0, stream>>>(src, dst, off2D, binned);
    k_csr   <<<NBKT, 256, 0, stream>>>(binned, off2D, col, off, dis);
    k_wsplit_both<<<32, 256, 0, stream>>>(W1, Wf1, W2, Wf2);

    // layer 1 aggregation: agg1 = A xb   (agg1 overwrites binned, now dead)
    k_agg_bf<false, false><<<N_NODES / 4, 256, 0, stream>>>(xb, col, off, dis, nullptr, agg1);
    // fused GEMMs: t2b = bf16( relu(agg1@W1+b1) @ W2 )   (overwrites xb, now dead)
    k_gemm_fused<<<(N_NODES + 31) / 32, 128, 0, stream>>>(agg1, Wf1, b1, Wf2, t2b, N_NODES);
    // layer 2 aggregation: out = relu(A t2b + b2)
    k_agg_bf<true, true><<<N_NODES / 4, 256, 0, stream>>>(t2b, col, off, dis, b2, out);
}

// Round 10
// 150.936 us; speedup vs baseline: 2.6416x; 1.0979x over previous
//
#include <hip/hip_runtime.h>

#define N_NODES 50000
#define N_EDGES 800000
#define IN_CH 128
#define HID_CH 256
#define OUT_CH 128

constexpr int TOTAL_E = N_EDGES + N_NODES;       // edges + self loops in CSR
constexpr int NBKT = 196;                        // buckets of 256 nodes (dst>>8)
constexpr int NBLK_BIN = 128;                    // binning blocks
constexpr int EPB_BIN = N_EDGES / NBLK_BIN;      // 6250 (exact)
constexpr int CNT2D = NBKT * NBLK_BIN;           // 25088
constexpr int SCAN_BLK = 1024;
constexpr int NB_SC = (CNT2D + SCAN_BLK - 1) / SCAN_BLK;  // 25
constexpr int COLCAP = 5376;                     // bucket edges cap + 256 selfloops

typedef __attribute__((ext_vector_type(8))) short bf16x8;
typedef __attribute__((ext_vector_type(4))) float f32x4;
typedef __attribute__((ext_vector_type(4))) unsigned int u32x4;

// ---------------- bf16 helpers ----------------

__device__ __forceinline__ unsigned int bf16rn(float x) {
    unsigned int u = __float_as_uint(x);
    return (u + 0x7fffu + ((u >> 16) & 1u)) >> 16;   // round-to-nearest-even
}

__device__ __forceinline__ void split2(float x0, float x1,
                                       unsigned int& h, unsigned int& l) {
    unsigned int h0 = bf16rn(x0), h1 = bf16rn(x1);
    float f0 = __uint_as_float(h0 << 16), f1 = __uint_as_float(h1 << 16);
    unsigned int l0 = bf16rn(x0 - f0), l1 = bf16rn(x1 - f1);
    h = h0 | (h1 << 16);
    l = l0 | (l1 << 16);
}

__device__ __forceinline__ bf16x8 asbf(u32x4 v) {
    return __builtin_bit_cast(bf16x8, v);
}

// ---------------- fp32 -> bf16 row copy ----------------

__global__ void k_tobf(const float* __restrict__ x, unsigned short* __restrict__ xb,
                       int n8) {
    int i = blockIdx.x * blockDim.x + threadIdx.x;
    if (i >= n8) return;
    const float4* p = (const float4*)(x + (size_t)i * 8);
    float4 a = p[0], b = p[1];
    u32x4 w;
    w.x = bf16rn(a.x) | (bf16rn(a.y) << 16);
    w.y = bf16rn(a.z) | (bf16rn(a.w) << 16);
    w.z = bf16rn(b.x) | (bf16rn(b.y) << 16);
    w.w = bf16rn(b.z) | (bf16rn(b.w) << 16);
    *(u32x4*)(xb + (size_t)i * 8) = w;
}

// ------------- CSR build: LDS radix binning (unchanged from R9, proven) -------------

__global__ __launch_bounds__(256)
void k_count(const int* __restrict__ dst, int* __restrict__ cnt2D) {
    __shared__ int h[NBKT];
    int b = blockIdx.x, t = threadIdx.x;
    if (t < NBKT) h[t] = 0;
    __syncthreads();
    int e0 = b * EPB_BIN;
    for (int i = t; i < EPB_BIN; i += 256)
        atomicAdd(&h[dst[e0 + i] >> 8], 1);
    __syncthreads();
    if (t < NBKT) cnt2D[t * NBLK_BIN + b] = h[t];
}

__global__ void k_scan1(const int* __restrict__ cnt, int* __restrict__ incl,
                        int* __restrict__ part, int n) {
    __shared__ int s[SCAN_BLK];
    int t = threadIdx.x;
    int i = blockIdx.x * SCAN_BLK + t;
    int v = (i < n) ? cnt[i] : 0;
    s[t] = v; __syncthreads();
    for (int o = 1; o < SCAN_BLK; o <<= 1) {
        int a = (t >= o) ? s[t - o] : 0;
        __syncthreads();
        s[t] += a;
        __syncthreads();
    }
    if (i < n) incl[i] = s[t];
    if (t == SCAN_BLK - 1) part[blockIdx.x] = s[t];
}

__global__ void k_scan2(int* __restrict__ part, int n) {
    __shared__ int s[SCAN_BLK];
    int t = threadIdx.x;
    int v = (t < n) ? part[t] : 0;
    s[t] = v; __syncthreads();
    for (int o = 1; o < SCAN_BLK; o <<= 1) {
        int a = (t >= o) ? s[t - o] : 0;
        __syncthreads();
        s[t] += a;
        __syncthreads();
    }
    if (t < n) part[t] = s[t] - v;    // exclusive
}

__global__ void k_off(int* __restrict__ incl, const int* __restrict__ cnt,
                      const int* __restrict__ part, int n, int total) {
    int i = blockIdx.x * blockDim.x + threadIdx.x;
    if (i < n)       incl[i] = part[i >> 10] + incl[i] - cnt[i];
    else if (i == n) incl[i] = total;
}

__global__ __launch_bounds__(256)
void k_bin(const int* __restrict__ src, const int* __restrict__ dst,
           const int* __restrict__ off2D, int2* __restrict__ binned) {
    __shared__ int cur[NBKT];
    int b = blockIdx.x, t = threadIdx.x;
    if (t < NBKT) cur[t] = off2D[t * NBLK_BIN + b];
    __syncthreads();
    int e0 = b * EPB_BIN;
    for (int i = t; i < EPB_BIN; i += 256) {
        int d = dst[e0 + i];
        int pos = atomicAdd(&cur[d >> 8], 1);
        int2 p; p.x = src[e0 + i]; p.y = d;
        binned[pos] = p;
    }
}

__global__ __launch_bounds__(256)
void k_csr(const int2* __restrict__ binned, const int* __restrict__ off2D,
           int* __restrict__ col, int* __restrict__ off, float* __restrict__ dis) {
    __shared__ int cnt[256], sc[256], cur[256];
    __shared__ int colL[COLCAP];
    int kb = blockIdx.x, t = threadIdx.x;
    int base2 = off2D[kb * NBLK_BIN];
    int end2  = off2D[(kb + 1) * NBLK_BIN];   // kb==NBKT-1 hits sentinel
    int nE = end2 - base2;
    int nn = min(256, N_NODES - kb * 256);
    cnt[t] = 0;
    __syncthreads();
    for (int i = t; i < nE; i += 256)
        atomicAdd(&cnt[binned[base2 + i].y & 255], 1);
    __syncthreads();
    sc[t] = cnt[t];
    __syncthreads();
    for (int o = 1; o < 256; o <<= 1) {
        int a = (t >= o) ? sc[t - o] : 0;
        __syncthreads();
        sc[t] += a;
        __syncthreads();
    }
    int excl = sc[t] - cnt[t];
    cur[t] = excl + t;            // +t: one self-loop slot per preceding node
    __syncthreads();
    for (int i = t; i < nE; i += 256) {
        int2 p = binned[base2 + i];
        colL[atomicAdd(&cur[p.y & 255], 1)] = p.x;
    }
    __syncthreads();
    int v = kb * 256 + t;
    if (t < nn) {
        colL[cur[t]] = v;         // self loop at segment end
        off[v] = base2 + kb * 256 + excl + t;
        dis[v] = rsqrtf((float)(cnt[t] + 1));
    }
    if (kb == NBKT - 1 && t == 0) off[N_NODES] = TOTAL_E;
    __syncthreads();
    int tot = nE + nn, gbase = base2 + kb * 256;
    for (int i = t; i < tot; i += 256)
        col[gbase + i] = colL[i];
}

// ---- bf16 aggregation: out[v] = sum_{c} dis[c]*dis[v] * featb[c]  (F = 128) ----
// BF16OUT: write bf16 (feeds the fused GEMM's A directly).

template<bool BIAS, bool RELU, bool BF16OUT>
__global__ __launch_bounds__(256)
void k_agg_bf(const unsigned short* __restrict__ featb, const int* __restrict__ col,
              const int* __restrict__ off, const float* __restrict__ dis,
              const float* __restrict__ bias, void* __restrict__ outv) {
    int wid  = threadIdx.x >> 6;
    int lane = threadIdx.x & 63;
    int v = blockIdx.x * 4 + wid;          // grid is exactly N_NODES/4
    int start = off[v];
    int lenv  = off[v + 1] - start;
    float disv = dis[v];
    int half = lane >> 5;
    int q    = lane & 31;
    float4 acc = make_float4(0.f, 0.f, 0.f, 0.f);
    for (int base = 0; base < lenv; base += 64) {
        int n = min(64, lenv - base);
        int   cv = 0;
        float wv = 0.f;
        if (lane < n) {
            cv = col[start + base + lane];
            wv = dis[cv] * disv;
        }
        auto pair = [&](int j) {
            int   c = __shfl(cv, j + half);   // j+half==n on odd tail -> w=0, c=0
            float w = __shfl(wv, j + half);
            uint2 d = *(const uint2*)&featb[(size_t)c * 128 + q * 4];
            acc.x = fmaf(w, __uint_as_float(d.x << 16),         acc.x);
            acc.y = fmaf(w, __uint_as_float(d.x & 0xffff0000u), acc.y);
            acc.z = fmaf(w, __uint_as_float(d.y << 16),         acc.z);
            acc.w = fmaf(w, __uint_as_float(d.y & 0xffff0000u), acc.w);
        };
        int j = 0;
        for (; j + 8 <= n; j += 8) { pair(j); pair(j + 2); pair(j + 4); pair(j + 6); }
        for (; j < n; j += 2) pair(j);
    }
    acc.x += __shfl_xor(acc.x, 32);
    acc.y += __shfl_xor(acc.y, 32);
    acc.z += __shfl_xor(acc.z, 32);
    acc.w += __shfl_xor(acc.w, 32);
    if (half == 0) {
        float4 o = acc;
        if (BIAS) {
            float4 b = *(const float4*)&bias[q * 4];
            o.x += b.x; o.y += b.y; o.z += b.z; o.w += b.w;
        }
        if (RELU) {
            o.x = fmaxf(o.x, 0.f); o.y = fmaxf(o.y, 0.f);
            o.z = fmaxf(o.z, 0.f); o.w = fmaxf(o.w, 0.f);
        }
        if (BF16OUT) {
            uint2 p;
            p.x = bf16rn(o.x) | (bf16rn(o.y) << 16);
            p.y = bf16rn(o.z) | (bf16rn(o.w) << 16);
            *(uint2*)&((unsigned short*)outv)[(size_t)v * 128 + q * 4] = p;
        } else {
            *(float4*)&((float*)outv)[(size_t)v * 128 + q * 4] = o;
        }
    }
}

// ---- W split into MFMA-fragment-ordered bf16 hi/lo (both layers, one launch) ----
// Fragment layout (16x16x32 bf16): B col n = lane&15, k = (lane>>4)*8 + i.

template<int K, int NC>
__device__ __forceinline__ void wsplit_body(const float* __restrict__ W,
                                            u32x4* __restrict__ Wf, int tid) {
    constexpr int NT = NC / 16;
    int lane = tid & 63;
    int ntk  = tid >> 6;
    int kt = ntk / NT, nt = ntk % NT;
    int kb = kt * 32 + (lane >> 4) * 8;
    int n  = nt * 16 + (lane & 15);
    unsigned int hh[4], ll[4];
    #pragma unroll
    for (int j = 0; j < 4; ++j) {
        float x0 = W[(size_t)(kb + 2 * j) * NC + n];
        float x1 = W[(size_t)(kb + 2 * j + 1) * NC + n];
        split2(x0, x1, hh[j], ll[j]);
    }
    Wf[(size_t)(ntk * 2 + 0) * 64 + lane] = (u32x4){hh[0], hh[1], hh[2], hh[3]};
    Wf[(size_t)(ntk * 2 + 1) * 64 + lane] = (u32x4){ll[0], ll[1], ll[2], ll[3]};
}

__global__ void k_wsplit_both(const float* __restrict__ W1, u32x4* __restrict__ Wf1,
                              const float* __restrict__ W2, u32x4* __restrict__ Wf2) {
    int tid = blockIdx.x * blockDim.x + threadIdx.x;
    if (tid < 4096)      wsplit_body<IN_CH,  HID_CH>(W1, Wf1, tid);
    else if (tid < 8192) wsplit_body<HID_CH, OUT_CH>(W2, Wf2, tid - 4096);
}

// ---- Fused GEMM: t2 = relu(Ab@W1+b1) @ W2; Ab bf16 [M,128], t2 bf16 [M,128] ----
// 4 waves/block, 32 rows/block. A single-bf16, W hi/lo (2-pass MFMA: A*Wh + A*Wl).
// h1 tile (32x256) lives only in LDS as single bf16 (XOR-swizzled), 16 KB.

__global__ __launch_bounds__(256)
void k_gemm_fused(const unsigned short* __restrict__ Ab, const u32x4* __restrict__ Wf1,
                  const float* __restrict__ b1, const u32x4* __restrict__ Wf2,
                  unsigned short* __restrict__ outb, int M) {
    __shared__ unsigned short hh[32 * 256];
    int lane = threadIdx.x & 63, wid = threadIdx.x >> 6;
    int lq = lane >> 4, lr = lane & 15, kq = lq * 8;
    int rbase = blockIdx.x * 32;

    // ---- GEMM1: 32x128 @ 128x256; each wave owns 4 of 16 N-tiles ----
    f32x4 acc[2][4];
    #pragma unroll
    for (int s = 0; s < 2; ++s)
        #pragma unroll
        for (int t = 0; t < 4; ++t) acc[s][t] = (f32x4){0.f, 0.f, 0.f, 0.f};

    for (int kt = 0; kt < 4; ++kt) {
        bf16x8 ah[2];
        #pragma unroll
        for (int s = 0; s < 2; ++s) {
            int row = min(rbase + s * 16 + lr, M - 1);
            ah[s] = *(const bf16x8*)&Ab[(size_t)row * IN_CH + kt * 32 + kq];
        }
        #pragma unroll
        for (int t = 0; t < 4; ++t) {
            int nt = wid * 4 + t;
            const u32x4* wp = Wf1 + (size_t)((kt * 16 + nt) * 2) * 64 + lane;
            bf16x8 bh = asbf(wp[0]);
            bf16x8 bl = asbf(wp[64]);
            acc[0][t] = __builtin_amdgcn_mfma_f32_16x16x32_bf16(ah[0], bh, acc[0][t], 0, 0, 0);
            acc[1][t] = __builtin_amdgcn_mfma_f32_16x16x32_bf16(ah[1], bh, acc[1][t], 0, 0, 0);
            acc[0][t] = __builtin_amdgcn_mfma_f32_16x16x32_bf16(ah[0], bl, acc[0][t], 0, 0, 0);
            acc[1][t] = __builtin_amdgcn_mfma_f32_16x16x32_bf16(ah[1], bl, acc[1][t], 0, 0, 0);
        }
    }

    // epilogue1: bias+relu -> single bf16 into LDS (XOR-swizzled rows)
    #pragma unroll
    for (int t = 0; t < 4; ++t) {
        int colg = (wid * 4 + t) * 16 + lr;
        float bv = b1[colg];
        #pragma unroll
        for (int s = 0; s < 2; ++s) {
            #pragma unroll
            for (int j = 0; j < 4; ++j) {
                int row = s * 16 + lq * 4 + j;
                float o = fmaxf(acc[s][t][j] + bv, 0.f);
                int e = (row * 256 + colg) ^ ((row & 7) << 3);
                hh[e] = (unsigned short)bf16rn(o);
            }
        }
    }
    __syncthreads();

    // ---- GEMM2: 32x256 @ 256x128; each wave owns 2 of 8 N-tiles ----
    f32x4 acc2[2][2];
    #pragma unroll
    for (int s = 0; s < 2; ++s)
        #pragma unroll
        for (int t = 0; t < 2; ++t) acc2[s][t] = (f32x4){0.f, 0.f, 0.f, 0.f};

    for (int kt = 0; kt < 8; ++kt) {
        bf16x8 ah[2];
        #pragma unroll
        for (int s = 0; s < 2; ++s) {
            int row = s * 16 + lr;
            int e = (row * 256 + kt * 32 + kq) ^ ((row & 7) << 3);
            ah[s] = *(const bf16x8*)&hh[e];
        }
        #pragma unroll
        for (int t = 0; t < 2; ++t) {
            int nt = wid * 2 + t;
            const u32x4* wp = Wf2 + (size_t)((kt * 8 + nt) * 2) * 64 + lane;
            bf16x8 bh = asbf(wp[0]);
            bf16x8 bl = asbf(wp[64]);
            acc2[0][t] = __builtin_amdgcn_mfma_f32_16x16x32_bf16(ah[0], bh, acc2[0][t], 0, 0, 0);
            acc2[1][t] = __builtin_amdgcn_mfma_f32_16x16x32_bf16(ah[1], bh, acc2[1][t], 0, 0, 0);
            acc2[0][t] = __builtin_amdgcn_mfma_f32_16x16x32_bf16(ah[0], bl, acc2[0][t], 0, 0, 0);
            acc2[1][t] = __builtin_amdgcn_mfma_f32_16x16x32_bf16(ah[1], bl, acc2[1][t], 0, 0, 0);
        }
    }

    // epilogue2: t2 as bf16 (bias/relu applied by agg2)
    #pragma unroll
    for (int t = 0; t < 2; ++t) {
        int colg = (wid * 2 + t) * 16 + lr;
        #pragma unroll
        for (int s = 0; s < 2; ++s) {
            #pragma unroll
            for (int j = 0; j < 4; ++j) {
                int row = rbase + s * 16 + lq * 4 + j;
                if (row < M)
                    outb[(size_t)row * OUT_CH + colg] =
                        (unsigned short)bf16rn(acc2[s][t][j]);
            }
        }
    }
}

// ---------------- launch ----------------

extern "C" void kernel_launch(void* const* d_in, const int* in_sizes, int n_in,
                              void* d_out, int out_size, void* d_ws, size_t ws_size,
                              hipStream_t stream) {
    const float* x   = (const float*)d_in[0];
    const int*   ei  = (const int*)d_in[1];
    const int*   src = ei;
    const int*   dst = ei + N_EDGES;
    const float* W1  = (const float*)d_in[3];
    const float* b1  = (const float*)d_in[4];
    const float* W2  = (const float*)d_in[5];
    const float* b2  = (const float*)d_in[6];
    float* out = (float*)d_out;

    char* ws = (char*)d_ws;
    size_t o = 0;
    auto carve = [&](size_t bytes) {
        void* p = ws + o;
        o += (bytes + 255) & ~(size_t)255;
        return p;
    };
    int*   cnt2D  = (int*)  carve((size_t)CNT2D * 4);
    int*   incl2D = (int*)  carve((size_t)(CNT2D + 1) * 4);  // becomes off2D
    int*   part   = (int*)  carve(SCAN_BLK * 4);
    int*   off    = (int*)  carve((size_t)(N_NODES + 1) * 4);
    float* dis    = (float*)carve(N_NODES * 4);
    int*   col    = (int*)  carve((size_t)TOTAL_E * 4);
    char*  buf1   = (char*) carve((size_t)N_NODES * 128 * 2);  // binned / agg1b
    unsigned short* bfbuf = (unsigned short*)carve((size_t)N_NODES * 128 * 2);
    u32x4* Wf1    = (u32x4*)carve((size_t)4 * 16 * 2 * 64 * 16);
    u32x4* Wf2    = (u32x4*)carve((size_t)8 * 8 * 2 * 64 * 16);
    int*   off2D  = incl2D;                // in-place exclusive scan
    // Aliases (lifetimes by launch order):
    //   binned aliases buf1 : written by k_bin (6.4 MB), read by k_csr, dead after
    //   agg1b  aliases buf1 : written by agg1 (12.8 MB, after binned dead)
    //   xb  = bfbuf         : written by k_tobf, read by agg1, dead after
    //   t2b = bfbuf         : written by fused gemm (xb dead), read by agg2
    int2*           binned = (int2*)buf1;
    unsigned short* agg1b  = (unsigned short*)buf1;
    unsigned short* xb     = bfbuf;
    unsigned short* t2b    = bfbuf;

    const int B = 256;
    k_tobf  <<<(N_NODES * 128 / 8 + B - 1) / B, B, 0, stream>>>(x, xb, N_NODES * 128 / 8);
    k_count <<<NBLK_BIN, 256, 0, stream>>>(dst, cnt2D);
    k_scan1 <<<NB_SC, SCAN_BLK, 0, stream>>>(cnt2D, incl2D, part, CNT2D);
    k_scan2 <<<1, SCAN_BLK, 0, stream>>>(part, NB_SC);
    k_off   <<<(CNT2D + 1 + B - 1) / B, B, 0, stream>>>(incl2D, cnt2D, part, CNT2D, N_EDGES);
    k_bin   <<<NBLK_BIN, 256, 0, stream>>>(src, dst, off2D, binned);
    k_csr   <<<NBKT, 256, 0, stream>>>(binned, off2D, col, off, dis);
    k_wsplit_both<<<32, 256, 0, stream>>>(W1, Wf1, W2, Wf2);

    // layer 1 aggregation: agg1b = bf16(A xb)   (overwrites binned, now dead)
    k_agg_bf<false, false, true><<<N_NODES / 4, 256, 0, stream>>>(
        xb, col, off, dis, nullptr, agg1b);
    // fused GEMMs: t2b = bf16( relu(agg1b@W1+b1) @ W2 )   (overwrites xb, now dead)
    k_gemm_fused<<<(N_NODES + 31) / 32, 256, 0, stream>>>(agg1b, Wf1, b1, Wf2, t2b, N_NODES);
    // layer 2 aggregation: out = relu(A t2b + b2)
    k_agg_bf<true, true, false><<<N_NODES / 4, 256, 0, stream>>>(
        t2b, col, off, dis, b2, out);
}